// Round 6
// baseline (1179.634 us; speedup 1.0000x reference)
//
#include <hip/hip_runtime.h>

typedef unsigned short u16;
typedef unsigned int u32;
typedef unsigned long long u64;

#define N_SITES 500000
#define CIN 32
#define COUT 32
#define DD 128
#define HHH 128
#define WWW 128
#define KVOL 125
#define EPSV 1e-4f
#define NVOX (4*DD*HHH*WWW)           // 8,388,608 = 8192 * 1024
#define RED_BLOCKS 512
#define CNT_BLOCKS 8192
#define NSLOT 500224                  // 1954 * 256 (padded site slots)
#define TILE 256
#define SROW 36                       // padded LDS acc row stride (floats); 144B, 16B-aligned

typedef short v8s __attribute__((ext_vector_type(8)));
typedef float v4f __attribute__((ext_vector_type(4)));

// ---------- helpers ----------
__device__ __forceinline__ u16 f2bf(float f){
  union { float f; u32 i; } v; v.f = f;
  u32 r = v.i + 0x7fffu + ((v.i >> 16) & 1u);
  return (u16)(r >> 16);
}

// ---------- BN stage 1: per-block partial sums (f32 input) ----------
__launch_bounds__(256)
__global__ void bn_reduce(const float* __restrict__ x, float* __restrict__ partial){
  __shared__ float ssum[8][32], ssq[8][32];
  int tid = threadIdx.x;
  int c   = tid & 31;
  int row = tid >> 5;
  float s = 0.f, q = 0.f;
  for(int site = blockIdx.x*8 + row; site < N_SITES; site += gridDim.x*8){
    float f = x[(size_t)site*32 + c];
    s += f; q += f*f;
  }
  ssum[row][c] = s; ssq[row][c] = q;
  __syncthreads();
  if(tid < 32){
    float ts = 0.f, tq = 0.f;
    #pragma unroll
    for(int r = 0; r < 8; r++){ ts += ssum[r][tid]; tq += ssq[r][tid]; }
    partial[blockIdx.x*64 + tid]      = ts;
    partial[blockIdx.x*64 + 32 + tid] = tq;
  }
}

// ---------- BN stage 2: finalize scale/shift ----------
__global__ void bn_finalize(const float* __restrict__ partial, const float* __restrict__ gamma,
                            const float* __restrict__ beta, float* __restrict__ ss, int nblk){
  int tid = threadIdx.x;
  if(tid >= 32) return;
  float s = 0.f, q = 0.f;
  for(int b = 0; b < nblk; b++){
    s += partial[b*64 + tid];
    q += partial[b*64 + 32 + tid];
  }
  float mean = s / (float)N_SITES;
  float var  = q / (float)N_SITES - mean*mean;   // biased, matches reference
  float scale = gamma[tid] * rsqrtf(var + EPSV);
  ss[tid]      = scale;
  ss[32 + tid] = beta[tid] - mean*scale;
}

// ---------- y = bf16(relu(x*scale+shift)) into workspace ----------
__launch_bounds__(256)
__global__ void bn_apply_y(const float4* __restrict__ xv, const float* __restrict__ ss,
                           uint4* __restrict__ yv){
  __shared__ float sc[64];
  int tid = threadIdx.x;
  if(tid < 64) sc[tid] = ss[tid];
  __syncthreads();
  const int total = N_SITES*CIN/8;            // 2,000,000 chunks of 8
  int stride = gridDim.x*256;
  for(int i = blockIdx.x*256 + tid; i < total; i += stride){
    int c0 = (i & 3) * 8;
    float4 a = xv[2*i], b = xv[2*i+1];
    float f[8] = {a.x,a.y,a.z,a.w,b.x,b.y,b.z,b.w};
    #pragma unroll
    for(int j = 0; j < 8; j++) f[j] = fmaxf(f[j]*sc[c0+j] + sc[32+c0+j], 0.f);
    uint4 o;
    o.x = ((u32)f2bf(f[1])<<16) | f2bf(f[0]);
    o.y = ((u32)f2bf(f[3])<<16) | f2bf(f[2]);
    o.z = ((u32)f2bf(f[5])<<16) | f2bf(f[4]);
    o.w = ((u32)f2bf(f[7])<<16) | f2bf(f[6]);
    yv[i] = o;
  }
}

// ---------- scatter site indices into grid + per-1024-voxel-block counts ----------
__launch_bounds__(256)
__global__ void build_grid(const int4* __restrict__ coords, int* __restrict__ grid,
                           int* __restrict__ blockcnt){
  int i = blockIdx.x*256 + threadIdx.x;
  if(i >= N_SITES) return;
  int4 c = coords[i];  // (b, z, y, x)
  int flat = ((c.x*DD + c.y)*HHH + c.z)*WWW + c.w;
  grid[flat] = i;
  atomicAdd(&blockcnt[flat >> 10], 1);
}

// ---------- exclusive prefix over 8192 block counts (one block) ----------
__launch_bounds__(1024)
__global__ void scan_blocks(const int* __restrict__ blockcnt, int* __restrict__ blockoff){
  __shared__ int s[1024];
  int t = threadIdx.x;
  int loc[8]; int v = 0;
  #pragma unroll
  for(int k = 0; k < 8; k++){ loc[k] = blockcnt[t*8 + k]; v += loc[k]; }
  s[t] = v; __syncthreads();
  for(int o = 1; o < 1024; o <<= 1){
    int add = (t >= o) ? s[t - o] : 0;
    __syncthreads();
    s[t] += add;
    __syncthreads();
  }
  int base = s[t] - v;
  #pragma unroll
  for(int k = 0; k < 8; k++){ blockoff[t*8 + k] = base; base += loc[k]; }
}

// ---------- ordered compaction: perm[j] = site ids in ascending voxel order ----------
__launch_bounds__(256)
__global__ void fill_perm(const int* __restrict__ grid, const int* __restrict__ blockoff,
                          int* __restrict__ perm){
  int b = blockIdx.x, t = threadIdx.x;
  int w = t >> 6, lane = t & 63;
  __shared__ int wcnt[4];
  __shared__ int carry;
  if(t == 0) carry = 0;
  __syncthreads();
  int base = blockoff[b];
  for(int p = 0; p < 4; p++){
    int v = b*1024 + p*256 + t;
    int s = grid[v];
    bool act = (s >= 0);
    u64 bal = __ballot(act);
    int pre = (int)__popcll(bal & ((1ull << lane) - 1ull));
    if(lane == 0) wcnt[w] = (int)__popcll(bal);
    __syncthreads();
    int woff = 0;
    for(int ww = 0; ww < w; ww++) woff += wcnt[ww];
    if(act) perm[base + carry + woff + pre] = s;
    int tot = wcnt[0] + wcnt[1] + wcnt[2] + wcnt[3];
    __syncthreads();
    if(t == 0) carry += tot;
    __syncthreads();
  }
}

// ---------- pad perm slots [N_SITES, NSLOT) with a valid site id ----------
__global__ void pad_perm(int* __restrict__ perm){
  int t = threadIdx.x;
  if(t < NSLOT - N_SITES) perm[N_SITES + t] = perm[0];
}

// ---------- pack W f32 [125][cin][cout] into bf16 MFMA B-fragment order ----------
// wf element index i = ((off*2 + tile)*64 + lane)*8 + j
// value = W[off][k][n], k=(lane>>4)*8+j, n=tile*16+(lane&15)
__launch_bounds__(256)
__global__ void prep_wfrag(const float* __restrict__ w, u16* __restrict__ wf){
  int i = blockIdx.x*256 + threadIdx.x;
  if(i >= KVOL*2*64*8) return;
  int j    = i & 7;
  int lane = (i >> 3) & 63;
  int tile = (i >> 9) & 1;
  int off  = i >> 10;
  int k = ((lane >> 4) << 3) + j;
  int n = (tile << 4) + (lane & 15);
  wf[i] = f2bf(w[off*1024 + k*32 + n]);
}

// ---------- submanifold sparse conv: block=256 sites, LDS f32 accumulators ----------
// Per offset (waves own offsets w,w+4,...): probe 256 sites, ballot-compact valid
// (out_local,nidx) pairs -> wave-private LDS list -> dense M=16 MFMA chunks ->
// ds_add_f32 scatter into LDS acc. No block syncs in the main loop.
__launch_bounds__(256)
__global__ void conv_mfma(const u16* __restrict__ y, const int4* __restrict__ coords,
                          const u16* __restrict__ wf, const int* __restrict__ grid,
                          const int* __restrict__ perm, float* __restrict__ out){
  __shared__ float sacc[TILE*SROW];                       // 36,864 B
  __shared__ int   svb[TILE];                             //  1,024 B
  __shared__ int   szyx[TILE];                            //  1,024 B
  __shared__ int   sp[TILE];                              //  1,024 B
  __shared__ alignas(16) int pairbuf[4][256];             //  4,096 B

  int t = threadIdx.x;
  int w = t >> 6, l = t & 63;
  int m15 = l & 15, q = l >> 4;

  // meta fill + zero accumulators
  int slot = blockIdx.x*TILE + t;
  int p = perm[slot];
  int4 c = coords[p];                       // (b, z, y, x)
  int vb = ((c.x*DD + c.y)*HHH + c.z)*WWW + c.w;
  sp[t] = p; svb[t] = vb;
  szyx[t] = (c.y << 14) | (c.z << 7) | c.w;
  #pragma unroll
  for(int j = 0; j < TILE*SROW/256; j++)    // 36 floats per thread
    sacc[j*256 + t] = 0.f;
  __syncthreads();

  for(int off = w; off < KVOL; off += 4){
    int dzi = off/25, rm = off - dzi*25;
    int dz = dzi - 2, dy = rm/5 - 2, dx = rm - (rm/5)*5 - 2;
    int delta = (dz*HHH + dy)*WWW + dx;
    int cnt = 0;
    #pragma unroll
    for(int r = 0; r < 4; r++){
      int i = r*64 + l;
      int zyx = szyx[i];
      int z = (zyx >> 14) & 127, yy = (zyx >> 7) & 127, x = zyx & 127;
      int nidx = -1;
      if(((u32)(z+dz) < DD) & ((u32)(yy+dy) < HHH) & ((u32)(x+dx) < WWW))
        nidx = grid[svb[i] + delta];
      bool val = (nidx >= 0);
      u64 bal = __ballot(val);
      int rank = (int)__popcll(bal & ((1ull << l) - 1ull));
      if(val) pairbuf[w][cnt + rank] = (i << 19) | nidx;   // nidx < 2^19
      cnt += (int)__popcll(bal);
    }
    if(cnt == 0) continue;
    __threadfence_block();                  // pairbuf writes -> reads (same wave)

    const v8s* wfo = (const v8s*)(wf + off*1024);
    v8s b0 = wfo[l], b1 = wfo[64 + l];
    int nchunk = (cnt + 15) >> 4;
    for(int ch = 0; ch < nchunk; ch++){
      int ka = ch*16 + m15;
      int pka = pairbuf[w][ka];
      v8s a = (v8s){0,0,0,0,0,0,0,0};
      if(ka < cnt) a = *(const v8s*)(y + (size_t)(pka & 0x7FFFF)*32 + q*8);
      v4f d0 = __builtin_amdgcn_mfma_f32_16x16x32_bf16(a, b0, (v4f){0.f,0.f,0.f,0.f}, 0, 0, 0);
      v4f d1 = __builtin_amdgcn_mfma_f32_16x16x32_bf16(a, b1, (v4f){0.f,0.f,0.f,0.f}, 0, 0, 0);
      // scatter: C row x = pair ch*16+x, row index x = q*4+r2 for this lane
      int kbase = ch*16 + q*4;
      int4 prow = *(const int4*)&pairbuf[w][kbase];
      #pragma unroll
      for(int r2 = 0; r2 < 4; r2++){
        if(kbase + r2 < cnt){
          int ol = ((&prow.x)[r2]) >> 19;
          atomicAdd(&sacc[ol*SROW + m15],      d0[r2]);
          atomicAdd(&sacc[ol*SROW + 16 + m15], d1[r2]);
        }
      }
    }
  }
  __syncthreads();

  // writeback: 8 lanes cooperate per site row (128B contiguous stores)
  #pragma unroll
  for(int k = 0; k < 8; k++){
    int sidx = (t >> 3) + k*32;
    int col4 = t & 7;
    float4 v = *(const float4*)&sacc[sidx*SROW + col4*4];
    *(float4*)(out + (size_t)sp[sidx]*32 + col4*4) = v;
  }
}

extern "C" void kernel_launch(void* const* d_in, const int* in_sizes, int n_in,
                              void* d_out, int out_size, void* d_ws, size_t ws_size,
                              hipStream_t stream) {
  const float* feats  = (const float*)d_in[0];   // [N,32] f32
  const int4*  coords = (const int4*) d_in[1];   // [N,4] int32
  const float* gamma  = (const float*)d_in[2];   // [32] f32
  const float* beta   = (const float*)d_in[3];   // [32] f32
  const float* wght   = (const float*)d_in[4];   // [125,32,32] f32
  float* out = (float*)d_out;

  char* ws = (char*)d_ws;
  int*   grid     = (int*)  ws;                   // 33,554,432 B
  u16*   ybuf     = (u16*)  (ws + 33554432);      // 32,000,000 B
  u16*   wf       = (u16*)  (ws + 65554432);      //    256,000 B
  int*   perm     = (int*)  (ws + 65810432);      //  2,000,896 B
  int*   blockcnt = (int*)  (ws + 67811328);      //     32,768 B
  int*   blockoff = (int*)  (ws + 67844096);      //     32,768 B
  float* partial  = (float*)(ws + 67876864);      //    131,072 B
  float* ss       = (float*)(ws + 68007936);      //        256 B
  // total: 68,008,192 B (~64.9 MiB)

  hipMemsetAsync(grid, 0xFF, (size_t)NVOX*4, stream);      // grid = -1
  hipMemsetAsync(blockcnt, 0, (size_t)CNT_BLOCKS*4, stream);

  bn_reduce  <<<RED_BLOCKS, 256, 0, stream>>>(feats, partial);
  bn_finalize<<<1, 32, 0, stream>>>(partial, gamma, beta, ss, RED_BLOCKS);
  bn_apply_y <<<2048, 256, 0, stream>>>((const float4*)feats, ss, (uint4*)ybuf);

  build_grid <<<(N_SITES+255)/256, 256, 0, stream>>>(coords, grid, blockcnt);
  scan_blocks<<<1, 1024, 0, stream>>>(blockcnt, blockoff);
  fill_perm  <<<CNT_BLOCKS, 256, 0, stream>>>(grid, blockoff, perm);
  pad_perm   <<<1, 256, 0, stream>>>(perm);

  prep_wfrag<<<(KVOL*2*64*8 + 255)/256, 256, 0, stream>>>(wght, wf);

  conv_mfma<<<NSLOT/TILE, 256, 0, stream>>>(ybuf, coords, wf, grid, perm, out);
}